// Round 11
// baseline (483.473 us; speedup 1.0000x reference)
//
#include <hip/hip_runtime.h>

#define NN 50000
#define NE 800000
#define NOUT (NN * 128)
#define PF_TOTAL 100608

typedef unsigned int u32;
typedef unsigned short u16;

typedef __attribute__((ext_vector_type(4))) float f32x4;
typedef __attribute__((ext_vector_type(8))) short bf16x8;

__device__ __forceinline__ float bf2f(u16 u) { return __uint_as_float(((u32)u) << 16); }
__device__ __forceinline__ u32 f2bf_u(float f) {
  u32 u = __float_as_uint(f);
  u += 0x7FFFu + ((u >> 16) & 1u);
  return u >> 16;
}
__device__ __forceinline__ u32 pk2(float a, float b) {
  return f2bf_u(a) | (f2bf_u(b) << 16);
}
__device__ __forceinline__ float lo_f(u32 v) { return __uint_as_float(v << 16); }
__device__ __forceinline__ float hi_f(u32 v) { return __uint_as_float(v & 0xFFFF0000u); }
__device__ __forceinline__ float h2f(u16 h) {
  u32 sg = ((u32)h >> 15) & 1u, e = ((u32)h >> 10) & 0x1Fu, mm = (u32)h & 0x3FFu;
  u32 o;
  if (e == 0u) o = sg << 31;
  else if (e == 31u) o = (sg << 31) | 0x7F800000u | (mm << 13);
  else o = (sg << 31) | ((e + 112u) << 23) | (mm << 13);
  return __uint_as_float(o);
}
__device__ __forceinline__ float lrelu(float x) { return x > 0.f ? x : 0.2f * x; }
__device__ __forceinline__ u32 umin32(u32 a, u32 b) { return a < b ? a : b; }

// fmode: 0=bf16, 1=fp32 (measured reality), 2=fp16
__device__ __forceinline__ float cvt_one(const void* p, int j, u32 fmode) {
  if (fmode == 1u) return ((const float*)p)[j];
  if (fmode == 2u) return h2f(((const u16*)p)[j]);
  return bf2f(((const u16*)p)[j]);
}

// identifier-named kernel retained (unused)
__global__ __launch_bounds__(256) void MultiScaleGNN_54769422958784_kernel(
    float* out, float val, int n) {
  int i = blockIdx.x * 256 + threadIdx.x;
  if (i < n) out[i] = val;
}

__global__ __launch_bounds__(64) void detect_kernel(const u32* lng, const int* ei,
                                                    u32* flag) {
  if (threadIdx.x == 0) {
    u32 v0 = lng[0], v1 = lng[1];
    u32 fm;
    if (v0 == 0x3F803F80u && v1 == 0x3F803F80u) fm = 0u;
    else if (v0 == 0x3F800000u && v1 == 0x3F800000u) fm = 1u;
    else if (v0 == 0x3C003C00u && v1 == 0x3C003C00u) fm = 2u;
    else fm = 1u;
    flag[0] = fm;
    flag[1] = ((ei[1] | ei[3] | ei[5] | ei[7]) == 0) ? 1u : 0u;
  }
}

// x -> packed bf16 [N,64]u32
__global__ __launch_bounds__(256) void cvt_x_kernel(const void* in, u32* outh, int n64,
                                                    const u32* flag) {
  u32 fm = flag[0];
  int i = blockIdx.x * 256 + threadIdx.x;
  if (i >= n64) return;
  int node = i >> 6, w = i & 63;
  float a = cvt_one(in, node * 128 + w * 2, fm);
  float b = cvt_one(in, node * 128 + w * 2 + 1, fm);
  outh[i] = pk2(a, b);
}

__global__ __launch_bounds__(256) void cvt_params_kernel(const void* g0, const void* g1,
                                                         const void* g2, const void* g3,
                                                         const void* g4, const void* g5,
                                                         const void* g6, const void* g7,
                                                         float* out, const u32* flag) {
  u32 fm = flag[0];
  int i = blockIdx.x * 256 + threadIdx.x;
  if (i >= PF_TOTAL) return;
  int offs[9] = {0, 49152, 49536, 98688, 99072, 99456, 99840, 100224, 100608};
  const void* ptrs[8] = {g0, g1, g2, g3, g4, g5, g6, g7};
  int r = 0;
  while (i >= offs[r + 1]) r++;
  out[i] = cvt_one(ptrs[r], i - offs[r], fm);
}

// 6 weight matrices (3 gcn + 3 gat) fp32 [k][n] -> transposed packed bf16 WT [n][k/2]u32
__global__ __launch_bounds__(256) void cvt_wt_kernel(const float* __restrict__ pf,
                                                     u32* __restrict__ wt) {
  int i = blockIdx.x * 256 + threadIdx.x;
  if (i >= 49152) return;
  int mat = i >> 13;       // 0..5
  int rem = i & 8191;
  int kk = rem >> 7;       // 0..63 (u32 index along k)
  int n = rem & 127;       // coalesced reads
  const float* W = pf + (mat < 3 ? (size_t)mat * 16384 : 49536 + (size_t)(mat - 3) * 16384);
  float a = W[(2 * kk) * 128 + n];
  float b = W[(2 * kk + 1) * 128 + n];
  wt[(size_t)mat * 8192 + n * 64 + kk] = pk2(a, b);
}

__global__ __launch_bounds__(256) void zero1_kernel(u32* a, int n) {
  int i = blockIdx.x * 256 + threadIdx.x;
  if (i < n) a[i] = 0u;
}

// rank pass: per-edge rank within its dst + final counts (one returning-atomic pass)
__global__ __launch_bounds__(256) void rank_kernel(const int* ei, u32* cnt, u32* rank,
                                                   int e, int n, const u32* flag) {
  int i = blockIdx.x * blockDim.x + threadIdx.x;
  if (i >= e) return;
  int d = flag[1] ? ei[2 * e + 2 * i] : ei[e + i];
  u32 r = 0u;
  if ((u32)d < (u32)n) r = atomicAdd(&cnt[d], 1u);
  rank[i] = r;
}

// ---- multi-block exclusive scan of counts -> rowptr (+dinv) ----
__device__ __forceinline__ u32 wave_incl_scan(u32 v, int lane) {
#pragma unroll
  for (int off = 1; off < 64; off <<= 1) {
    u32 t = (u32)__shfl_up((int)v, off);
    if (lane >= off) v += t;
  }
  return v;
}

__global__ __launch_bounds__(256) void scan_sum_kernel(const u32* counts, u32* bsums,
                                                       int n) {
  __shared__ u32 ws[4];
  int i = blockIdx.x * 256 + threadIdx.x;
  int lane = threadIdx.x & 63, wid = threadIdx.x >> 6;
  u32 c = (i < n) ? counts[i] : 0u;
#pragma unroll
  for (int off = 32; off; off >>= 1) c += (u32)__shfl_xor((int)c, off);
  if (lane == 0) ws[wid] = c;
  __syncthreads();
  if (threadIdx.x == 0) bsums[blockIdx.x] = ws[0] + ws[1] + ws[2] + ws[3];
}

__global__ __launch_bounds__(256) void scan_bsums_kernel(u32* bsums, u32* rowptr, int nb,
                                                         int n) {
  __shared__ u32 ws[4];
  int tid = threadIdx.x, lane = tid & 63, wid = tid >> 6;
  u32 v = (tid < nb) ? bsums[tid] : 0u;
  u32 incl = wave_incl_scan(v, lane);
  if (lane == 63) ws[wid] = incl;
  __syncthreads();
  u32 wo = 0u;
  for (int w = 0; w < wid; w++) wo += ws[w];
  u32 excl = incl - v + wo;
  if (tid < nb) bsums[tid] = excl;
  if (tid == 0) rowptr[n] = ws[0] + ws[1] + ws[2] + ws[3];
}

__global__ __launch_bounds__(256) void scan_write_kernel(const u32* counts,
                                                         const u32* bsums, u32* rowptr,
                                                         float* dinv, int n) {
  __shared__ u32 ws[4];
  int b = blockIdx.x;
  int i = b * 256 + threadIdx.x;
  int lane = threadIdx.x & 63, wid = threadIdx.x >> 6;
  u32 c = (i < n) ? counts[i] : 0u;
  u32 incl = wave_incl_scan(c, lane);
  if (lane == 63) ws[wid] = incl;
  __syncthreads();
  u32 wo = bsums[b];
  for (int w = 0; w < wid; w++) wo += ws[w];
  u32 excl = incl - c + wo;
  if (i < n) {
    rowptr[i] = excl;
    dinv[i] = rsqrtf((float)(c + 1u));
  }
}

// place pass: NO atomics (rank precomputed)
__global__ __launch_bounds__(256) void place_kernel(const int* ei, const u32* rowptr,
                                                    const u32* rank, int* col, int e,
                                                    int n, const u32* flag) {
  int i = blockIdx.x * blockDim.x + threadIdx.x;
  if (i >= e) return;
  u32 em = flag[1];
  int s = em ? ei[2 * i] : ei[i];
  int d = em ? ei[2 * e + 2 * i] : ei[e + i];
  if ((u32)d >= (u32)n) return;
  u32 p = rowptr[d] + rank[i];
  if (p < (u32)e) col[p] = ((u32)s < (u32)n) ? s : 0;
}

// MFMA GEMM v4: 48 rows/wave (3 row-groups), 192 rows/block. W-load instructions
// are the conserved cost (v1/v2/v3 evidence) -> 3 MFMA per W-load cuts total
// W-loads to 2/3 of v1. Occupancy ~1 wave/SIMD is fine (v3: occupancy-neutral).
__global__ __launch_bounds__(256) void gemm_mfma_kernel(
    const u32* __restrict__ Ah, const u32* __restrict__ WTh, u32* __restrict__ Oh,
    const float* __restrict__ dinv, const float* __restrict__ att_s,
    const float* __restrict__ att_d, float* __restrict__ asrc,
    float* __restrict__ adst, int M) {
  int tid = threadIdx.x;
  int wave = tid >> 6, lane = tid & 63;
  int p = lane & 15, g = lane >> 4;
  int r0 = blockIdx.x * 192 + wave * 48;
  int ra = r0 + p, rb = r0 + 16 + p, rc = r0 + 32 + p;
  int rac = min(ra, M - 1), rbc = min(rb, M - 1), rcc = min(rc, M - 1);

  const u32* apA = Ah + (size_t)rac * 64 + g * 4;
  const u32* apB = Ah + (size_t)rbc * 64 + g * 4;
  const u32* apC = Ah + (size_t)rcc * 64 + g * 4;
  uint4 bA[4], bB[4], bC[4];
#pragma unroll
  for (int k0 = 0; k0 < 4; k0++) {
    bA[k0] = *(const uint4*)(apA + k0 * 16);
    bB[k0] = *(const uint4*)(apB + k0 * 16);
    bC[k0] = *(const uint4*)(apC + k0 * 16);
  }

  f32x4 acc0[8], acc1[8], acc2[8];
#pragma unroll
  for (int t = 0; t < 8; t++) {
    acc0[t] = (f32x4)0.f;
    acc1[t] = (f32x4)0.f;
    acc2[t] = (f32x4)0.f;
  }

  const u32* wp = WTh + p * 64 + g * 4;
#pragma unroll
  for (int k0 = 0; k0 < 4; k0++) {
    bf16x8 fa = __builtin_bit_cast(bf16x8, bA[k0]);
    bf16x8 fb = __builtin_bit_cast(bf16x8, bB[k0]);
    bf16x8 fc = __builtin_bit_cast(bf16x8, bC[k0]);
#pragma unroll
    for (int t = 0; t < 8; t++) {
      uint4 af = *(const uint4*)(wp + t * 1024 + k0 * 16);
      bf16x8 aw = __builtin_bit_cast(bf16x8, af);
      acc0[t] = __builtin_amdgcn_mfma_f32_16x16x32_bf16(aw, fa, acc0[t], 0, 0, 0);
      acc1[t] = __builtin_amdgcn_mfma_f32_16x16x32_bf16(aw, fb, acc1[t], 0, 0, 0);
      acc2[t] = __builtin_amdgcn_mfma_f32_16x16x32_bf16(aw, fc, acc2[t], 0, 0, 0);
    }
  }

#pragma unroll
  for (int i = 0; i < 3; i++) {
    int r = r0 + i * 16 + p;
    if (r < M) {
      float sc = dinv ? dinv[r] : 1.0f;
      u32* orow = Oh + (size_t)r * 64;
      float hs[4] = {0.f, 0.f, 0.f, 0.f};
      float hd[4] = {0.f, 0.f, 0.f, 0.f};
#pragma unroll
      for (int t = 0; t < 8; t++) {
        f32x4 v = (i == 0) ? acc0[t] : (i == 1) ? acc1[t] : acc2[t];
        float v0 = v[0] * sc, v1 = v[1] * sc, v2 = v[2] * sc, v3 = v[3] * sc;
        *(uint2*)(orow + t * 8 + g * 2) = make_uint2(pk2(v0, v1), pk2(v2, v3));
        if (att_s) {
          float4 wsv = *(const float4*)(att_s + t * 16 + g * 4);
          float4 wdv = *(const float4*)(att_d + t * 16 + g * 4);
          int h = t >> 1;
          hs[h] += v0 * wsv.x + v1 * wsv.y + v2 * wsv.z + v3 * wsv.w;
          hd[h] += v0 * wdv.x + v1 * wdv.y + v2 * wdv.z + v3 * wdv.w;
        }
      }
      if (att_s) {
#pragma unroll
        for (int h = 0; h < 4; h++) {
          hs[h] += __shfl_xor(hs[h], 16);
          hs[h] += __shfl_xor(hs[h], 32);
          hd[h] += __shfl_xor(hd[h], 16);
          hd[h] += __shfl_xor(hd[h], 32);
        }
        if (g == 0) {
          *(float4*)(asrc + (size_t)r * 4) = make_float4(hs[0], hs[1], hs[2], hs[3]);
          *(float4*)(adst + (size_t)r * 4) = make_float4(hd[0], hd[1], hd[2], hd[3]);
        }
      }
    }
  }
}

// GCN aggregation (R2-proven): 32 lanes/node, 4 ch/lane, uint2 loads.
__global__ __launch_bounds__(256) void gcn_agg_kernel(const u32* __restrict__ xh,
                                                      const int* col, const u32* rowptr,
                                                      const float* dinv, const float* bias,
                                                      u32* __restrict__ outh, int n) {
  __shared__ int lds_s[8][32];
  int g = threadIdx.x >> 5;
  int l = threadIdx.x & 31;
  int d = blockIdx.x * 8 + g;
  if (d >= n) return;
  u32 start = umin32(rowptr[d], (u32)NE), end = umin32(rowptr[d + 1], (u32)NE);
  float4 acc = make_float4(0.f, 0.f, 0.f, 0.f);
  for (u32 base = start; base < end; base += 32) {
    u32 i = base + l;
    int cnt = (int)umin32(32u, end - base);
    if (i < end) lds_s[g][l] = col[i];
#pragma unroll 4
    for (int j = 0; j < cnt; j++) {
      int s = lds_s[g][j];
      uint2 v = *(const uint2*)(xh + (size_t)s * 64 + l * 2);
      acc.x += lo_f(v.x);
      acc.y += hi_f(v.x);
      acc.z += lo_f(v.y);
      acc.w += hi_f(v.y);
    }
  }
  int c0 = l * 4;
  uint2 sv = *(const uint2*)(xh + (size_t)d * 64 + l * 2);
  float dd = dinv[d];
  float o0 = dd * (acc.x + lo_f(sv.x)) + bias[c0];
  float o1 = dd * (acc.y + hi_f(sv.x)) + bias[c0 + 1];
  float o2 = dd * (acc.z + lo_f(sv.y)) + bias[c0 + 2];
  float o3 = dd * (acc.w + hi_f(sv.y)) + bias[c0 + 3];
  *(uint2*)(outh + (size_t)d * 64 + l * 2) = make_uint2(pk2(o0, o1), pk2(o2, o3));
}

// GAT aggregation v4 (R7/R8-verified numerics): single-pass softmax, no online max.
__global__ __launch_bounds__(256) void gat_agg_kernel(
    const u32* __restrict__ xh, const float* a_src4, const float* a_dst4, const int* col,
    const u32* rowptr, const u32* __restrict__ hgcnh, const float* gat_b,
    const float* ln_g, const float* ln_b, u32* __restrict__ outh,
    float* __restrict__ outf, int n) {
  __shared__ u32 lds_s[8][32];
  __shared__ float lds_ee[8][32][4];
  int g = threadIdx.x >> 5;
  int l = threadIdx.x & 31;
  int head4 = l >> 3;
  int d = blockIdx.x * 8 + g;
  if (d >= n) return;
  u32 start = umin32(rowptr[d], (u32)NE), end = umin32(rowptr[d + 1], (u32)NE);
  float4 ad = *(const float4*)(a_dst4 + (size_t)d * 4);
  float4 asl = *(const float4*)(a_src4 + (size_t)d * 4);
  float4 ees;
  ees.x = __expf(lrelu(asl.x + ad.x));
  ees.y = __expf(lrelu(asl.y + ad.y));
  ees.z = __expf(lrelu(asl.z + ad.z));
  ees.w = __expf(lrelu(asl.w + ad.w));
  float4 zp = make_float4(0.f, 0.f, 0.f, 0.f);
  float4 acc = make_float4(0.f, 0.f, 0.f, 0.f);
  for (u32 base = start; base < end; base += 32) {
    u32 i = base + l;
    int cnt = (int)umin32(32u, end - base);
    bool act = i < end;
    if (act) {
      int s = col[i];
      float4 a = *(const float4*)(a_src4 + (size_t)s * 4);
      float ex = __expf(lrelu(a.x + ad.x));
      float ey = __expf(lrelu(a.y + ad.y));
      float ez = __expf(lrelu(a.z + ad.z));
      float ew = __expf(lrelu(a.w + ad.w));
      zp.x += ex;
      zp.y += ey;
      zp.z += ez;
      zp.w += ew;
      lds_s[g][l] = (u32)s;
      *(float4*)&lds_ee[g][l][0] = make_float4(ex, ey, ez, ew);
    }
#pragma unroll 4
    for (int j = 0; j < cnt; j++) {
      u32 sg = lds_s[g][j];
      float w = lds_ee[g][j][head4];
      uint2 v = *(const uint2*)(xh + (size_t)sg * 64 + l * 2);
      acc.x = fmaf(w, lo_f(v.x), acc.x);
      acc.y = fmaf(w, hi_f(v.x), acc.y);
      acc.z = fmaf(w, lo_f(v.y), acc.z);
      acc.w = fmaf(w, hi_f(v.y), acc.w);
    }
  }
#pragma unroll
  for (int off = 16; off; off >>= 1) {
    zp.x += __shfl_xor(zp.x, off);
    zp.y += __shfl_xor(zp.y, off);
    zp.z += __shfl_xor(zp.z, off);
    zp.w += __shfl_xor(zp.w, off);
  }
  zp.x += ees.x;
  zp.y += ees.y;
  zp.z += ees.z;
  zp.w += ees.w;
  float wsel = (head4 == 0) ? ees.x : (head4 == 1) ? ees.y : (head4 == 2) ? ees.z : ees.w;
  float zsel = (head4 == 0) ? zp.x : (head4 == 1) ? zp.y : (head4 == 2) ? zp.z : zp.w;
  int c0 = l * 4;
  uint2 sv = *(const uint2*)(xh + (size_t)d * 64 + l * 2);
  acc.x = fmaf(wsel, lo_f(sv.x), acc.x);
  acc.y = fmaf(wsel, hi_f(sv.x), acc.y);
  acc.z = fmaf(wsel, lo_f(sv.y), acc.z);
  acc.w = fmaf(wsel, hi_f(sv.y), acc.w);
  float rz = 1.0f / zsel;
  uint2 hgv = *(const uint2*)(hgcnh + (size_t)d * 64 + l * 2);
  float t0 = acc.x * rz + gat_b[c0] + lo_f(hgv.x);
  float t1 = acc.y * rz + gat_b[c0 + 1] + hi_f(hgv.x);
  float t2 = acc.z * rz + gat_b[c0 + 2] + lo_f(hgv.y);
  float t3 = acc.w * rz + gat_b[c0 + 3] + hi_f(hgv.y);
  float ssum = t0 + t1 + t2 + t3;
#pragma unroll
  for (int off = 16; off; off >>= 1) ssum += __shfl_xor(ssum, off);
  float mu = ssum * (1.0f / 128.0f);
  float d0 = t0 - mu, d1 = t1 - mu, d2 = t2 - mu, d3 = t3 - mu;
  float vv = d0 * d0 + d1 * d1 + d2 * d2 + d3 * d3;
#pragma unroll
  for (int off = 16; off; off >>= 1) vv += __shfl_xor(vv, off);
  float rstd = rsqrtf(vv * (1.0f / 128.0f) + 1e-5f);
  float o0 = fmaxf(fmaf(d0 * rstd, ln_g[c0], ln_b[c0]), 0.f);
  float o1 = fmaxf(fmaf(d1 * rstd, ln_g[c0 + 1], ln_b[c0 + 1]), 0.f);
  float o2 = fmaxf(fmaf(d2 * rstd, ln_g[c0 + 2], ln_b[c0 + 2]), 0.f);
  float o3 = fmaxf(fmaf(d3 * rstd, ln_g[c0 + 3], ln_b[c0 + 3]), 0.f);
  if (outf) {
    *(float4*)(outf + (size_t)d * 128 + c0) = make_float4(o0, o1, o2, o3);
  } else {
    *(uint2*)(outh + (size_t)d * 64 + l * 2) = make_uint2(pk2(o0, o1), pk2(o2, o3));
  }
}

extern "C" void kernel_launch(void* const* d_in, const int* in_sizes, int n_in,
                              void* d_out, int out_size, void* d_ws, size_t ws_size,
                              hipStream_t stream) {
  const int N = NN, E = NE;
  (void)in_sizes;
  (void)n_in;
  (void)out_size;
  (void)ws_size;

  // ---- workspace layout ----
  char* ws = (char*)d_ws;
  size_t off = 0;
  u32* xwh = (u32*)(ws + off);      off += (size_t)N * 64 * 4;
  u32* hbufh = (u32*)(ws + off);    off += (size_t)N * 64 * 4;
  u32* hgcnh = (u32*)(ws + off);    off += (size_t)N * 64 * 4;
  float* asrc = (float*)(ws + off); off += (size_t)N * 4 * 4;
  float* adst = (float*)(ws + off); off += (size_t)N * 4 * 4;
  float* dinv = (float*)(ws + off); off += (size_t)N * 4;
  u32* counts = (u32*)(ws + off);   off += (size_t)N * 4;
  u32* rowptr = (u32*)(ws + off);   off += (size_t)(N + 1) * 4 + 252;
  u32* rank = (u32*)(ws + off);     off += (size_t)E * 4;
  int* col = (int*)(ws + off);      off += (size_t)E * 4;
  float* pf = (float*)(ws + off);   off += (size_t)PF_TOTAL * 4;
  u32* wt = (u32*)(ws + off);       off += (size_t)49152 * 4;
  u32* bsums = (u32*)(ws + off);    off += 256 * 4;
  u32* flag = (u32*)(ws + off);     off += 256;

  // ---- input conversion + CSR build ----
  const int* edge_index = (const int*)d_in[1];
  detect_kernel<<<1, 64, 0, stream>>>((const u32*)d_in[8], edge_index, flag);
  cvt_params_kernel<<<(PF_TOTAL + 255) / 256, 256, 0, stream>>>(
      d_in[2], d_in[3], d_in[4], d_in[5], d_in[6], d_in[7], d_in[8], d_in[9], pf, flag);
  cvt_wt_kernel<<<(49152 + 255) / 256, 256, 0, stream>>>(pf, wt);
  cvt_x_kernel<<<(N * 64 + 255) / 256, 256, 0, stream>>>(d_in[0], hbufh, N * 64, flag);
  zero1_kernel<<<(N + 255) / 256, 256, 0, stream>>>(counts, N);
  rank_kernel<<<(E + 255) / 256, 256, 0, stream>>>(edge_index, counts, rank, E, N, flag);
  {
    int nb = (N + 255) / 256;  // 196 <= 256
    scan_sum_kernel<<<nb, 256, 0, stream>>>(counts, bsums, N);
    scan_bsums_kernel<<<1, 256, 0, stream>>>(bsums, rowptr, nb, N);
    scan_write_kernel<<<nb, 256, 0, stream>>>(counts, bsums, rowptr, dinv, N);
  }
  place_kernel<<<(E + 255) / 256, 256, 0, stream>>>(edge_index, rowptr, rank, col, E, N,
                                                    flag);

  const float* att_s = pf + 98688;
  const float* att_d = pf + 99072;
  const float* gcn_b = pf + 49152;
  const float* gat_b = pf + 99456;
  const float* ln_g = pf + 99840;
  const float* ln_b = pf + 100224;

  // ---- 3 layers ----
  int gblocks = (N + 191) / 192;  // 261: 192 rows/block, 48 rows/wave
  int ablocks = (N + 7) / 8;
  for (int l = 0; l < 3; l++) {
    gemm_mfma_kernel<<<gblocks, 256, 0, stream>>>(
        hbufh, wt + (size_t)l * 8192, xwh, dinv, (const float*)0, (const float*)0,
        (float*)0, (float*)0, N);
    gcn_agg_kernel<<<ablocks, 256, 0, stream>>>(xwh, col, rowptr, dinv, gcn_b + l * 128,
                                                hgcnh, N);
    gemm_mfma_kernel<<<gblocks, 256, 0, stream>>>(
        hgcnh, wt + (size_t)(3 + l) * 8192, xwh, (const float*)0, att_s + l * 128,
        att_d + l * 128, asrc, adst, N);
    gat_agg_kernel<<<ablocks, 256, 0, stream>>>(
        xwh, asrc, adst, col, rowptr, hgcnh, gat_b + l * 128, ln_g + l * 128,
        ln_b + l * 128, hbufh, (l < 2) ? (float*)0 : (float*)d_out, N);
  }
}

// Round 12
// 472.124 us; speedup vs baseline: 1.0240x; 1.0240x over previous
//
#include <hip/hip_runtime.h>

#define NN 50000
#define NE 800000
#define NOUT (NN * 128)
#define PF_TOTAL 100608

typedef unsigned int u32;
typedef unsigned short u16;

typedef __attribute__((ext_vector_type(4))) float f32x4;
typedef __attribute__((ext_vector_type(8))) short bf16x8;

__device__ __forceinline__ float bf2f(u16 u) { return __uint_as_float(((u32)u) << 16); }
__device__ __forceinline__ u32 f2bf_u(float f) {
  u32 u = __float_as_uint(f);
  u += 0x7FFFu + ((u >> 16) & 1u);
  return u >> 16;
}
__device__ __forceinline__ u32 pk2(float a, float b) {
  return f2bf_u(a) | (f2bf_u(b) << 16);
}
__device__ __forceinline__ float lo_f(u32 v) { return __uint_as_float(v << 16); }
__device__ __forceinline__ float hi_f(u32 v) { return __uint_as_float(v & 0xFFFF0000u); }
__device__ __forceinline__ float h2f(u16 h) {
  u32 sg = ((u32)h >> 15) & 1u, e = ((u32)h >> 10) & 0x1Fu, mm = (u32)h & 0x3FFu;
  u32 o;
  if (e == 0u) o = sg << 31;
  else if (e == 31u) o = (sg << 31) | 0x7F800000u | (mm << 13);
  else o = (sg << 31) | ((e + 112u) << 23) | (mm << 13);
  return __uint_as_float(o);
}
__device__ __forceinline__ float lrelu(float x) { return x > 0.f ? x : 0.2f * x; }
__device__ __forceinline__ u32 umin32(u32 a, u32 b) { return a < b ? a : b; }

// fmode: 0=bf16, 1=fp32 (measured reality), 2=fp16
__device__ __forceinline__ float cvt_one(const void* p, int j, u32 fmode) {
  if (fmode == 1u) return ((const float*)p)[j];
  if (fmode == 2u) return h2f(((const u16*)p)[j]);
  return bf2f(((const u16*)p)[j]);
}

// identifier-named kernel retained (unused)
__global__ __launch_bounds__(256) void MultiScaleGNN_54769422958784_kernel(
    float* out, float val, int n) {
  int i = blockIdx.x * 256 + threadIdx.x;
  if (i < n) out[i] = val;
}

__global__ __launch_bounds__(64) void detect_kernel(const u32* lng, const int* ei,
                                                    u32* flag) {
  if (threadIdx.x == 0) {
    u32 v0 = lng[0], v1 = lng[1];
    u32 fm;
    if (v0 == 0x3F803F80u && v1 == 0x3F803F80u) fm = 0u;
    else if (v0 == 0x3F800000u && v1 == 0x3F800000u) fm = 1u;
    else if (v0 == 0x3C003C00u && v1 == 0x3C003C00u) fm = 2u;
    else fm = 1u;
    flag[0] = fm;
    flag[1] = ((ei[1] | ei[3] | ei[5] | ei[7]) == 0) ? 1u : 0u;
  }
}

// x -> packed bf16 [N,64]u32
__global__ __launch_bounds__(256) void cvt_x_kernel(const void* in, u32* outh, int n64,
                                                    const u32* flag) {
  u32 fm = flag[0];
  int i = blockIdx.x * 256 + threadIdx.x;
  if (i >= n64) return;
  int node = i >> 6, w = i & 63;
  float a = cvt_one(in, node * 128 + w * 2, fm);
  float b = cvt_one(in, node * 128 + w * 2 + 1, fm);
  outh[i] = pk2(a, b);
}

__global__ __launch_bounds__(256) void cvt_params_kernel(const void* g0, const void* g1,
                                                         const void* g2, const void* g3,
                                                         const void* g4, const void* g5,
                                                         const void* g6, const void* g7,
                                                         float* out, const u32* flag) {
  u32 fm = flag[0];
  int i = blockIdx.x * 256 + threadIdx.x;
  if (i >= PF_TOTAL) return;
  int offs[9] = {0, 49152, 49536, 98688, 99072, 99456, 99840, 100224, 100608};
  const void* ptrs[8] = {g0, g1, g2, g3, g4, g5, g6, g7};
  int r = 0;
  while (i >= offs[r + 1]) r++;
  out[i] = cvt_one(ptrs[r], i - offs[r], fm);
}

// 6 weight matrices (3 gcn + 3 gat) fp32 [k][n] -> transposed packed bf16 WT [n][k/2]u32
__global__ __launch_bounds__(256) void cvt_wt_kernel(const float* __restrict__ pf,
                                                     u32* __restrict__ wt) {
  int i = blockIdx.x * 256 + threadIdx.x;
  if (i >= 49152) return;
  int mat = i >> 13;       // 0..5
  int rem = i & 8191;
  int kk = rem >> 7;       // 0..63 (u32 index along k)
  int n = rem & 127;       // coalesced reads
  const float* W = pf + (mat < 3 ? (size_t)mat * 16384 : 49536 + (size_t)(mat - 3) * 16384);
  float a = W[(2 * kk) * 128 + n];
  float b = W[(2 * kk + 1) * 128 + n];
  wt[(size_t)mat * 8192 + n * 64 + kk] = pk2(a, b);
}

__global__ __launch_bounds__(256) void zero1_kernel(u32* a, int n) {
  int i = blockIdx.x * 256 + threadIdx.x;
  if (i < n) a[i] = 0u;
}

// rank pass: per-edge rank within its dst + final counts (one returning-atomic pass)
__global__ __launch_bounds__(256) void rank_kernel(const int* ei, u32* cnt, u32* rank,
                                                   int e, int n, const u32* flag) {
  int i = blockIdx.x * blockDim.x + threadIdx.x;
  if (i >= e) return;
  int d = flag[1] ? ei[2 * e + 2 * i] : ei[e + i];
  u32 r = 0u;
  if ((u32)d < (u32)n) r = atomicAdd(&cnt[d], 1u);
  rank[i] = r;
}

// ---- multi-block exclusive scan of counts -> rowptr (+dinv) ----
__device__ __forceinline__ u32 wave_incl_scan(u32 v, int lane) {
#pragma unroll
  for (int off = 1; off < 64; off <<= 1) {
    u32 t = (u32)__shfl_up((int)v, off);
    if (lane >= off) v += t;
  }
  return v;
}

__global__ __launch_bounds__(256) void scan_sum_kernel(const u32* counts, u32* bsums,
                                                       int n) {
  __shared__ u32 ws[4];
  int i = blockIdx.x * 256 + threadIdx.x;
  int lane = threadIdx.x & 63, wid = threadIdx.x >> 6;
  u32 c = (i < n) ? counts[i] : 0u;
#pragma unroll
  for (int off = 32; off; off >>= 1) c += (u32)__shfl_xor((int)c, off);
  if (lane == 0) ws[wid] = c;
  __syncthreads();
  if (threadIdx.x == 0) bsums[blockIdx.x] = ws[0] + ws[1] + ws[2] + ws[3];
}

__global__ __launch_bounds__(256) void scan_bsums_kernel(u32* bsums, u32* rowptr, int nb,
                                                         int n) {
  __shared__ u32 ws[4];
  int tid = threadIdx.x, lane = tid & 63, wid = tid >> 6;
  u32 v = (tid < nb) ? bsums[tid] : 0u;
  u32 incl = wave_incl_scan(v, lane);
  if (lane == 63) ws[wid] = incl;
  __syncthreads();
  u32 wo = 0u;
  for (int w = 0; w < wid; w++) wo += ws[w];
  u32 excl = incl - v + wo;
  if (tid < nb) bsums[tid] = excl;
  if (tid == 0) rowptr[n] = ws[0] + ws[1] + ws[2] + ws[3];
}

__global__ __launch_bounds__(256) void scan_write_kernel(const u32* counts,
                                                         const u32* bsums, u32* rowptr,
                                                         float* dinv, int n) {
  __shared__ u32 ws[4];
  int b = blockIdx.x;
  int i = b * 256 + threadIdx.x;
  int lane = threadIdx.x & 63, wid = threadIdx.x >> 6;
  u32 c = (i < n) ? counts[i] : 0u;
  u32 incl = wave_incl_scan(c, lane);
  if (lane == 63) ws[wid] = incl;
  __syncthreads();
  u32 wo = bsums[b];
  for (int w = 0; w < wid; w++) wo += ws[w];
  u32 excl = incl - c + wo;
  if (i < n) {
    rowptr[i] = excl;
    dinv[i] = rsqrtf((float)(c + 1u));
  }
}

// place pass: NO atomics (rank precomputed)
__global__ __launch_bounds__(256) void place_kernel(const int* ei, const u32* rowptr,
                                                    const u32* rank, int* col, int e,
                                                    int n, const u32* flag) {
  int i = blockIdx.x * blockDim.x + threadIdx.x;
  if (i >= e) return;
  u32 em = flag[1];
  int s = em ? ei[2 * i] : ei[i];
  int d = em ? ei[2 * e + 2 * i] : ei[e + i];
  if ((u32)d >= (u32)n) return;
  u32 p = rowptr[d] + rank[i];
  if (p < (u32)e) col[p] = ((u32)s < (u32)n) ? s : 0;
}

// MFMA GEMM (R8-proven best: v1 128 rows/block, 32 rows/wave, 2x W-frag reuse,
// lb(256,3)). v2/v3/v4 restructures all measured <= this; do not touch.
__global__ __launch_bounds__(256, 3) void gemm_mfma_kernel(
    const u32* __restrict__ Ah, const u32* __restrict__ WTh, u32* __restrict__ Oh,
    const float* __restrict__ dinv, const float* __restrict__ att_s,
    const float* __restrict__ att_d, float* __restrict__ asrc,
    float* __restrict__ adst, int M) {
  int tid = threadIdx.x;
  int wave = tid >> 6, lane = tid & 63;
  int p = lane & 15, g = lane >> 4;
  int r0 = blockIdx.x * 128 + wave * 32;
  int ra = r0 + p, rb = r0 + 16 + p;
  int rac = min(ra, M - 1), rbc = min(rb, M - 1);

  const u32* apA = Ah + (size_t)rac * 64 + g * 4;
  const u32* apB = Ah + (size_t)rbc * 64 + g * 4;
  uint4 bA[4], bB[4];
#pragma unroll
  for (int k0 = 0; k0 < 4; k0++) {
    bA[k0] = *(const uint4*)(apA + k0 * 16);
    bB[k0] = *(const uint4*)(apB + k0 * 16);
  }

  f32x4 acc0[8], acc1[8];
#pragma unroll
  for (int t = 0; t < 8; t++) {
    acc0[t] = (f32x4)0.f;
    acc1[t] = (f32x4)0.f;
  }

  const u32* wp = WTh + p * 64 + g * 4;
#pragma unroll
  for (int k0 = 0; k0 < 4; k0++) {
    bf16x8 fa = __builtin_bit_cast(bf16x8, bA[k0]);
    bf16x8 fb = __builtin_bit_cast(bf16x8, bB[k0]);
#pragma unroll
    for (int t = 0; t < 8; t++) {
      uint4 af = *(const uint4*)(wp + t * 1024 + k0 * 16);
      bf16x8 aw = __builtin_bit_cast(bf16x8, af);
      acc0[t] = __builtin_amdgcn_mfma_f32_16x16x32_bf16(aw, fa, acc0[t], 0, 0, 0);
      acc1[t] = __builtin_amdgcn_mfma_f32_16x16x32_bf16(aw, fb, acc1[t], 0, 0, 0);
    }
  }

#pragma unroll
  for (int i = 0; i < 2; i++) {
    int r = r0 + i * 16 + p;
    if (r < M) {
      float sc = dinv ? dinv[r] : 1.0f;
      u32* orow = Oh + (size_t)r * 64;
      float hs[4] = {0.f, 0.f, 0.f, 0.f};
      float hd[4] = {0.f, 0.f, 0.f, 0.f};
#pragma unroll
      for (int t = 0; t < 8; t++) {
        f32x4 v = (i == 0) ? acc0[t] : acc1[t];
        float v0 = v[0] * sc, v1 = v[1] * sc, v2 = v[2] * sc, v3 = v[3] * sc;
        *(uint2*)(orow + t * 8 + g * 2) = make_uint2(pk2(v0, v1), pk2(v2, v3));
        if (att_s) {
          float4 wsv = *(const float4*)(att_s + t * 16 + g * 4);
          float4 wdv = *(const float4*)(att_d + t * 16 + g * 4);
          int h = t >> 1;
          hs[h] += v0 * wsv.x + v1 * wsv.y + v2 * wsv.z + v3 * wsv.w;
          hd[h] += v0 * wdv.x + v1 * wdv.y + v2 * wdv.z + v3 * wdv.w;
        }
      }
      if (att_s) {
#pragma unroll
        for (int h = 0; h < 4; h++) {
          hs[h] += __shfl_xor(hs[h], 16);
          hs[h] += __shfl_xor(hs[h], 32);
          hd[h] += __shfl_xor(hd[h], 16);
          hd[h] += __shfl_xor(hd[h], 32);
        }
        if (g == 0) {
          *(float4*)(asrc + (size_t)r * 4) = make_float4(hs[0], hs[1], hs[2], hs[3]);
          *(float4*)(adst + (size_t)r * 4) = make_float4(hd[0], hd[1], hd[2], hd[3]);
        }
      }
    }
  }
}

// GCN aggregation (R2-proven): 32 lanes/node, 4 ch/lane, uint2 loads.
__global__ __launch_bounds__(256) void gcn_agg_kernel(const u32* __restrict__ xh,
                                                      const int* col, const u32* rowptr,
                                                      const float* dinv, const float* bias,
                                                      u32* __restrict__ outh, int n) {
  __shared__ int lds_s[8][32];
  int g = threadIdx.x >> 5;
  int l = threadIdx.x & 31;
  int d = blockIdx.x * 8 + g;
  if (d >= n) return;
  u32 start = umin32(rowptr[d], (u32)NE), end = umin32(rowptr[d + 1], (u32)NE);
  float4 acc = make_float4(0.f, 0.f, 0.f, 0.f);
  for (u32 base = start; base < end; base += 32) {
    u32 i = base + l;
    int cnt = (int)umin32(32u, end - base);
    if (i < end) lds_s[g][l] = col[i];
#pragma unroll 4
    for (int j = 0; j < cnt; j++) {
      int s = lds_s[g][j];
      uint2 v = *(const uint2*)(xh + (size_t)s * 64 + l * 2);
      acc.x += lo_f(v.x);
      acc.y += hi_f(v.x);
      acc.z += lo_f(v.y);
      acc.w += hi_f(v.y);
    }
  }
  int c0 = l * 4;
  uint2 sv = *(const uint2*)(xh + (size_t)d * 64 + l * 2);
  float dd = dinv[d];
  float o0 = dd * (acc.x + lo_f(sv.x)) + bias[c0];
  float o1 = dd * (acc.y + hi_f(sv.x)) + bias[c0 + 1];
  float o2 = dd * (acc.z + lo_f(sv.y)) + bias[c0 + 2];
  float o3 = dd * (acc.w + hi_f(sv.y)) + bias[c0 + 3];
  *(uint2*)(outh + (size_t)d * 64 + l * 2) = make_uint2(pk2(o0, o1), pk2(o2, o3));
}

// GAT aggregation v4 (R7/R8-verified numerics): single-pass softmax, no online max.
__global__ __launch_bounds__(256) void gat_agg_kernel(
    const u32* __restrict__ xh, const float* a_src4, const float* a_dst4, const int* col,
    const u32* rowptr, const u32* __restrict__ hgcnh, const float* gat_b,
    const float* ln_g, const float* ln_b, u32* __restrict__ outh,
    float* __restrict__ outf, int n) {
  __shared__ u32 lds_s[8][32];
  __shared__ float lds_ee[8][32][4];
  int g = threadIdx.x >> 5;
  int l = threadIdx.x & 31;
  int head4 = l >> 3;
  int d = blockIdx.x * 8 + g;
  if (d >= n) return;
  u32 start = umin32(rowptr[d], (u32)NE), end = umin32(rowptr[d + 1], (u32)NE);
  float4 ad = *(const float4*)(a_dst4 + (size_t)d * 4);
  float4 asl = *(const float4*)(a_src4 + (size_t)d * 4);
  float4 ees;
  ees.x = __expf(lrelu(asl.x + ad.x));
  ees.y = __expf(lrelu(asl.y + ad.y));
  ees.z = __expf(lrelu(asl.z + ad.z));
  ees.w = __expf(lrelu(asl.w + ad.w));
  float4 zp = make_float4(0.f, 0.f, 0.f, 0.f);
  float4 acc = make_float4(0.f, 0.f, 0.f, 0.f);
  for (u32 base = start; base < end; base += 32) {
    u32 i = base + l;
    int cnt = (int)umin32(32u, end - base);
    bool act = i < end;
    if (act) {
      int s = col[i];
      float4 a = *(const float4*)(a_src4 + (size_t)s * 4);
      float ex = __expf(lrelu(a.x + ad.x));
      float ey = __expf(lrelu(a.y + ad.y));
      float ez = __expf(lrelu(a.z + ad.z));
      float ew = __expf(lrelu(a.w + ad.w));
      zp.x += ex;
      zp.y += ey;
      zp.z += ez;
      zp.w += ew;
      lds_s[g][l] = (u32)s;
      *(float4*)&lds_ee[g][l][0] = make_float4(ex, ey, ez, ew);
    }
#pragma unroll 4
    for (int j = 0; j < cnt; j++) {
      u32 sg = lds_s[g][j];
      float w = lds_ee[g][j][head4];
      uint2 v = *(const uint2*)(xh + (size_t)sg * 64 + l * 2);
      acc.x = fmaf(w, lo_f(v.x), acc.x);
      acc.y = fmaf(w, hi_f(v.x), acc.y);
      acc.z = fmaf(w, lo_f(v.y), acc.z);
      acc.w = fmaf(w, hi_f(v.y), acc.w);
    }
  }
#pragma unroll
  for (int off = 16; off; off >>= 1) {
    zp.x += __shfl_xor(zp.x, off);
    zp.y += __shfl_xor(zp.y, off);
    zp.z += __shfl_xor(zp.z, off);
    zp.w += __shfl_xor(zp.w, off);
  }
  zp.x += ees.x;
  zp.y += ees.y;
  zp.z += ees.z;
  zp.w += ees.w;
  float wsel = (head4 == 0) ? ees.x : (head4 == 1) ? ees.y : (head4 == 2) ? ees.z : ees.w;
  float zsel = (head4 == 0) ? zp.x : (head4 == 1) ? zp.y : (head4 == 2) ? zp.z : zp.w;
  int c0 = l * 4;
  uint2 sv = *(const uint2*)(xh + (size_t)d * 64 + l * 2);
  acc.x = fmaf(wsel, lo_f(sv.x), acc.x);
  acc.y = fmaf(wsel, hi_f(sv.x), acc.y);
  acc.z = fmaf(wsel, lo_f(sv.y), acc.z);
  acc.w = fmaf(wsel, hi_f(sv.y), acc.w);
  float rz = 1.0f / zsel;
  uint2 hgv = *(const uint2*)(hgcnh + (size_t)d * 64 + l * 2);
  float t0 = acc.x * rz + gat_b[c0] + lo_f(hgv.x);
  float t1 = acc.y * rz + gat_b[c0 + 1] + hi_f(hgv.x);
  float t2 = acc.z * rz + gat_b[c0 + 2] + lo_f(hgv.y);
  float t3 = acc.w * rz + gat_b[c0 + 3] + hi_f(hgv.y);
  float ssum = t0 + t1 + t2 + t3;
#pragma unroll
  for (int off = 16; off; off >>= 1) ssum += __shfl_xor(ssum, off);
  float mu = ssum * (1.0f / 128.0f);
  float d0 = t0 - mu, d1 = t1 - mu, d2 = t2 - mu, d3 = t3 - mu;
  float vv = d0 * d0 + d1 * d1 + d2 * d2 + d3 * d3;
#pragma unroll
  for (int off = 16; off; off >>= 1) vv += __shfl_xor(vv, off);
  float rstd = rsqrtf(vv * (1.0f / 128.0f) + 1e-5f);
  float o0 = fmaxf(fmaf(d0 * rstd, ln_g[c0], ln_b[c0]), 0.f);
  float o1 = fmaxf(fmaf(d1 * rstd, ln_g[c0 + 1], ln_b[c0 + 1]), 0.f);
  float o2 = fmaxf(fmaf(d2 * rstd, ln_g[c0 + 2], ln_b[c0 + 2]), 0.f);
  float o3 = fmaxf(fmaf(d3 * rstd, ln_g[c0 + 3], ln_b[c0 + 3]), 0.f);
  if (outf) {
    *(float4*)(outf + (size_t)d * 128 + c0) = make_float4(o0, o1, o2, o3);
  } else {
    *(uint2*)(outh + (size_t)d * 64 + l * 2) = make_uint2(pk2(o0, o1), pk2(o2, o3));
  }
}

extern "C" void kernel_launch(void* const* d_in, const int* in_sizes, int n_in,
                              void* d_out, int out_size, void* d_ws, size_t ws_size,
                              hipStream_t stream) {
  const int N = NN, E = NE;
  (void)in_sizes;
  (void)n_in;
  (void)out_size;
  (void)ws_size;

  // ---- workspace layout ----
  char* ws = (char*)d_ws;
  size_t off = 0;
  u32* xwh = (u32*)(ws + off);      off += (size_t)N * 64 * 4;
  u32* hbufh = (u32*)(ws + off);    off += (size_t)N * 64 * 4;
  u32* hgcnh = (u32*)(ws + off);    off += (size_t)N * 64 * 4;
  float* asrc = (float*)(ws + off); off += (size_t)N * 4 * 4;
  float* adst = (float*)(ws + off); off += (size_t)N * 4 * 4;
  float* dinv = (float*)(ws + off); off += (size_t)N * 4;
  u32* counts = (u32*)(ws + off);   off += (size_t)N * 4;
  u32* rowptr = (u32*)(ws + off);   off += (size_t)(N + 1) * 4 + 252;
  u32* rank = (u32*)(ws + off);     off += (size_t)E * 4;
  int* col = (int*)(ws + off);      off += (size_t)E * 4;
  float* pf = (float*)(ws + off);   off += (size_t)PF_TOTAL * 4;
  u32* wt = (u32*)(ws + off);       off += (size_t)49152 * 4;
  u32* bsums = (u32*)(ws + off);    off += 256 * 4;
  u32* flag = (u32*)(ws + off);     off += 256;

  // ---- input conversion + CSR build ----
  const int* edge_index = (const int*)d_in[1];
  detect_kernel<<<1, 64, 0, stream>>>((const u32*)d_in[8], edge_index, flag);
  cvt_params_kernel<<<(PF_TOTAL + 255) / 256, 256, 0, stream>>>(
      d_in[2], d_in[3], d_in[4], d_in[5], d_in[6], d_in[7], d_in[8], d_in[9], pf, flag);
  cvt_wt_kernel<<<(49152 + 255) / 256, 256, 0, stream>>>(pf, wt);
  cvt_x_kernel<<<(N * 64 + 255) / 256, 256, 0, stream>>>(d_in[0], hbufh, N * 64, flag);
  zero1_kernel<<<(N + 255) / 256, 256, 0, stream>>>(counts, N);
  rank_kernel<<<(E + 255) / 256, 256, 0, stream>>>(edge_index, counts, rank, E, N, flag);
  {
    int nb = (N + 255) / 256;  // 196 <= 256
    scan_sum_kernel<<<nb, 256, 0, stream>>>(counts, bsums, N);
    scan_bsums_kernel<<<1, 256, 0, stream>>>(bsums, rowptr, nb, N);
    scan_write_kernel<<<nb, 256, 0, stream>>>(counts, bsums, rowptr, dinv, N);
  }
  place_kernel<<<(E + 255) / 256, 256, 0, stream>>>(edge_index, rowptr, rank, col, E, N,
                                                    flag);

  const float* att_s = pf + 98688;
  const float* att_d = pf + 99072;
  const float* gcn_b = pf + 49152;
  const float* gat_b = pf + 99456;
  const float* ln_g = pf + 99840;
  const float* ln_b = pf + 100224;

  // ---- 3 layers ----
  int gblocks = (N + 127) / 128;
  int ablocks = (N + 7) / 8;
  for (int l = 0; l < 3; l++) {
    gemm_mfma_kernel<<<gblocks, 256, 0, stream>>>(
        hbufh, wt + (size_t)l * 8192, xwh, dinv, (const float*)0, (const float*)0,
        (float*)0, (float*)0, N);
    gcn_agg_kernel<<<ablocks, 256, 0, stream>>>(xwh, col, rowptr, dinv, gcn_b + l * 128,
                                                hgcnh, N);
    gemm_mfma_kernel<<<gblocks, 256, 0, stream>>>(
        hgcnh, wt + (size_t)(3 + l) * 8192, xwh, (const float*)0, att_s + l * 128,
        att_d + l * 128, asrc, adst, N);
    gat_agg_kernel<<<ablocks, 256, 0, stream>>>(
        xwh, asrc, adst, col, rowptr, hgcnh, gat_b + l * 128, ln_g + l * 128,
        ln_b + l * 128, hbufh, (l < 2) ? (float*)0 : (float*)d_out, N);
  }
}